// Round 10
// baseline (352.719 us; speedup 1.0000x reference)
//
#include <hip/hip_runtime.h>

#define NN 100000
#define EE 600000
#define HH 128
#define GG 4000
#define TT 128

typedef short short8 __attribute__((ext_vector_type(8)));
typedef unsigned short ushort8v __attribute__((ext_vector_type(8)));
typedef float floatx4 __attribute__((ext_vector_type(4)));

static __device__ __forceinline__ float bf2f(unsigned short u) {
  union { unsigned int i; float f; } v; v.i = ((unsigned int)u) << 16; return v.f;
}
static __device__ __forceinline__ unsigned short f2bf(float f) {
  union { float f; unsigned int i; } v; v.f = f;
  unsigned int r = (v.i + 0x7FFFu + ((v.i >> 16) & 1u)) >> 16;   // RNE
  return (unsigned short)r;
}

#define DB ((EE / 4 + 255) / 256)    // 586 blocks, 4 edges/thread

// ---------------- kernel A: deg_count + atom encoder (unscaled) + wt --------
// blocks [0, DB)              : degree count, 4 edges/thread (int4)
// blocks [DB, DB+NN/16)       : atom encoder -> h0 = bf16(sum emb)  (UNSCALED)
// blocks [DB+NN/16, +192)     : Wt[n][k] = bf16(W[k][n]) for W1,W2,W3
__global__ __launch_bounds__(256) void pre_k(const int* __restrict__ ei,
                                             int* __restrict__ cnt,
                                             const int* __restrict__ x,
                                             const float* __restrict__ emb,
                                             unsigned short* __restrict__ h0,
                                             const float* __restrict__ W1,
                                             const float* __restrict__ W2,
                                             const float* __restrict__ W3,
                                             unsigned short* __restrict__ Wt) {
  if (blockIdx.x < DB) {
    int e4 = (blockIdx.x * 256 + threadIdx.x) * 4;
    if (e4 < EE) {   // EE % 4 == 0, all-or-nothing
      int4 d = *(const int4*)(ei + EE + e4);
      atomicAdd(&cnt[d.x], 1);
      atomicAdd(&cnt[d.y], 1);
      atomicAdd(&cnt[d.z], 1);
      atomicAdd(&cnt[d.w], 1);
    }
  } else if (blockIdx.x < DB + NN / 16) {
    const int lane = threadIdx.x & 63;
    const int wid  = threadIdx.x >> 6;
    const int l16  = lane & 15;
    const int n = (blockIdx.x - DB) * 16 + wid * 4 + (lane >> 4);
    const int off[9] = {0, 119, 124, 136, 148, 158, 164, 170, 172};
    int xv = (l16 < 9) ? x[n * 9 + l16] : 0;
    float s[8] = {0.f, 0.f, 0.f, 0.f, 0.f, 0.f, 0.f, 0.f};
#pragma unroll
    for (int f = 0; f < 9; f++) {
      int idx = __shfl(xv, (lane & 48) | f, 64) + off[f];
      const float* ep = emb + (size_t)idx * HH + l16 * 8;
      float4 e0 = *(const float4*)ep;
      float4 e1 = *(const float4*)(ep + 4);
      s[0] += e0.x; s[1] += e0.y; s[2] += e0.z; s[3] += e0.w;
      s[4] += e1.x; s[5] += e1.y; s[6] += e1.z; s[7] += e1.w;
    }
    ushort8v o;
#pragma unroll
    for (int j = 0; j < 8; j++) o[j] = f2bf(s[j]);
    *(ushort8v*)(h0 + (size_t)n * HH + l16 * 8) = o;
  } else {
    int f = (blockIdx.x - DB - NN / 16) * 256 + threadIdx.x;   // 0..49151
    int wsel = f >> 14;
    int r = (f >> 7) & 127;
    int k = f & 127;
    const float* W = (wsel == 0) ? W1 : (wsel == 1) ? W2 : W3;
    Wt[wsel * HH * HH + r * HH + k] = f2bf(W[k * HH + r]);
  }
}

// ---------------- CSR build: 3-kernel exclusive scan (+dinv fused) ----------
__global__ __launch_bounds__(256) void scan1_k(const int* __restrict__ cnt,
                                               int* __restrict__ ptr,
                                               int* __restrict__ bsum,
                                               float* __restrict__ dinv) {
  const int i = blockIdx.x * 256 + threadIdx.x;
  int v = (i < NN) ? cnt[i] : 0;
  if (i < NN) dinv[i] = rsqrtf((float)v + 1.0f);   // +1 self-loop
  const int lane = threadIdx.x & 63, wid = threadIdx.x >> 6;
  int s = v;
#pragma unroll
  for (int off = 1; off < 64; off <<= 1) {
    int t = __shfl_up(s, off, 64);
    if (lane >= off) s += t;
  }
  __shared__ int wt[4];
  if (lane == 63) wt[wid] = s;
  __syncthreads();
  int wadd = 0;
  for (int w = 0; w < wid; w++) wadd += wt[w];
  int incl = s + wadd;
  if (i < NN) ptr[i] = incl - v;
  if (threadIdx.x == 255) bsum[blockIdx.x] = incl;
}

__global__ __launch_bounds__(512) void scan2_k(int* __restrict__ bsum, int nb) {
  const int t = threadIdx.x;
  int v = (t < nb) ? bsum[t] : 0;
  const int lane = t & 63, wid = t >> 6;
  int s = v;
#pragma unroll
  for (int off = 1; off < 64; off <<= 1) {
    int u = __shfl_up(s, off, 64);
    if (lane >= off) s += u;
  }
  __shared__ int wt[8];
  if (lane == 63) wt[wid] = s;
  __syncthreads();
  int wadd = 0;
  for (int w = 0; w < wid; w++) wadd += wt[w];
  int incl = s + wadd;
  if (t < nb) bsum[t] = incl - v;
}

// scan3 + graph-boundary precompute (batch is sorted)
__global__ __launch_bounds__(256) void scan3_gb_k(int* __restrict__ ptr,
                                                  const int* __restrict__ bsum,
                                                  const int* __restrict__ batch,
                                                  int* __restrict__ gs) {
  const int i = blockIdx.x * 256 + threadIdx.x;
  if (i < NN) {
    ptr[i] += bsum[blockIdx.x];
    int b0 = batch[i];
    int b1 = (i + 1 < NN) ? batch[i + 1] : GG;
    for (int g = b0 + 1; g <= b1; g++) gs[g] = i + 1;
    if (i == 0) {
      ptr[NN] = EE;
      for (int g = 0; g <= b0; g++) gs[g] = 0;
    }
  }
}

// ---------------- CSR fill: 4 edges/thread (4 independent atomic chains) ----
__global__ __launch_bounds__(256) void fill_k(const int* __restrict__ ei,
                                              const int* __restrict__ ptr,
                                              int* __restrict__ cnt,
                                              int* __restrict__ csr) {
  int e4 = (blockIdx.x * 256 + threadIdx.x) * 4;
  if (e4 >= EE) return;
  int4 s = *(const int4*)(ei + e4);
  int4 d = *(const int4*)(ei + EE + e4);
  int o0 = atomicSub(&cnt[d.x], 1) - 1;
  int o1 = atomicSub(&cnt[d.y], 1) - 1;
  int o2 = atomicSub(&cnt[d.z], 1) - 1;
  int o3 = atomicSub(&cnt[d.w], 1) - 1;
  csr[ptr[d.x] + o0] = s.x;
  csr[ptr[d.y] + o1] = s.y;
  csr[ptr[d.z] + o2] = s.z;
  csr[ptr[d.w] + o3] = s.w;
}

// ---------------- CSR aggregation (masked full-unroll, csr prefetch) --------
// L1GATHER==true : Hs is UNSCALED h0; Aggs[n] = bf16(dn*(dn*h[n] + sum dinv[s]*h[s]))
// L1GATHER==false: Hs pre-scaled;     Aggs[n] = bf16(dn*(Hs[n] + sum Hs[s]))
template <bool L1GATHER>
__global__ __launch_bounds__(256) void agg_bf_k(const int* __restrict__ ptr,
                                                const int* __restrict__ csr,
                                                const unsigned short* __restrict__ Hs,
                                                const float* __restrict__ dinv,
                                                unsigned short* __restrict__ Aggs) {
  const int lane = threadIdx.x & 63;
  const int wid  = threadIdx.x >> 6;
  const int l16  = lane & 15;
  const int n = blockIdx.x * 16 + wid * 4 + (lane >> 4);   // grid*16 == NN
  const int beg = ptr[n], end = ptr[n + 1];
  const int last = end - 1;
  const float dn = dinv[n];
  float acc[8];
  {  // self row
    ushort8v v = *(const ushort8v*)(Hs + (size_t)n * HH + l16 * 8);
    const float sw = L1GATHER ? dn : 1.0f;
#pragma unroll
    for (int j = 0; j < 8; j++) acc[j] = sw * bf2f(v[j]);
  }
  int i = beg;
  if (i < end) {
    int c0 = csr[i];
    int c1 = csr[min(i + 1, last)];
    int c2 = csr[min(i + 2, last)];
    int c3 = csr[min(i + 3, last)];
    while (true) {
      float m0 = 1.f;
      float m1 = (i + 1 < end) ? 1.f : 0.f;
      float m2 = (i + 2 < end) ? 1.f : 0.f;
      float m3 = (i + 3 < end) ? 1.f : 0.f;
      if (L1GATHER) {
        m0 *= dinv[c0]; m1 *= dinv[c1]; m2 *= dinv[c2]; m3 *= dinv[c3];
      }
      ushort8v v0 = *(const ushort8v*)(Hs + (size_t)c0 * HH + l16 * 8);
      ushort8v v1 = *(const ushort8v*)(Hs + (size_t)c1 * HH + l16 * 8);
      ushort8v v2 = *(const ushort8v*)(Hs + (size_t)c2 * HH + l16 * 8);
      ushort8v v3 = *(const ushort8v*)(Hs + (size_t)c3 * HH + l16 * 8);
      const int ni = i + 4;
      int p0 = c0, p1 = c1, p2 = c2, p3 = c3;
      if (ni < end) {             // prefetch next csr quad (overlaps gathers)
        p0 = csr[ni];
        p1 = csr[min(ni + 1, last)];
        p2 = csr[min(ni + 2, last)];
        p3 = csr[min(ni + 3, last)];
      }
      if (L1GATHER) {
#pragma unroll
        for (int j = 0; j < 8; j++)
          acc[j] += m0 * bf2f(v0[j]) + m1 * bf2f(v1[j]) + m2 * bf2f(v2[j]) + m3 * bf2f(v3[j]);
      } else {
#pragma unroll
        for (int j = 0; j < 8; j++)
          acc[j] += bf2f(v0[j]) + m1 * bf2f(v1[j]) + m2 * bf2f(v2[j]) + m3 * bf2f(v3[j]);
      }
      i = ni;
      if (i >= end) break;
      c0 = p0; c1 = p1; c2 = p2; c3 = p3;
    }
  }
  ushort8v o;
#pragma unroll
  for (int j = 0; j < 8; j++) o[j] = f2bf(dn * acc[j]);
  *(ushort8v*)(Aggs + (size_t)n * HH + l16 * 8) = o;
}

// ---------------- MFMA GEMM (after aggregation) ----------------
template <bool LAST>
__global__ __launch_bounds__(256) void gemm_mfma_k(const unsigned short* __restrict__ A,
                                                   const unsigned short* __restrict__ Wt,
                                                   const float* __restrict__ b,
                                                   const float* __restrict__ dinv,
                                                   unsigned short* __restrict__ Out) {
  const int w = threadIdx.x >> 6;
  const int l = threadIdx.x & 63;
  const int m16 = l & 15;
  const int q8  = (l >> 4) * 8;
  const int bm  = blockIdx.x * 128 + w * 32;

  floatx4 acc[2][8];
#pragma unroll
  for (int i = 0; i < 2; i++)
#pragma unroll
    for (int j = 0; j < 8; j++) acc[i][j] = (floatx4){0.f, 0.f, 0.f, 0.f};

  for (int q = 0; q < 4; q++) {
    const int k0 = q * 32;
    short8 a[2];
#pragma unroll
    for (int ti = 0; ti < 2; ti++) {
      int row = bm + ti * 16 + m16;
      a[ti] = (row < NN) ? *(const short8*)(A + (size_t)row * HH + k0 + q8)
                         : (short8){0, 0, 0, 0, 0, 0, 0, 0};
    }
#pragma unroll
    for (int tn = 0; tn < 8; tn++) {
      short8 bf = *(const short8*)(Wt + (size_t)(tn * 16 + m16) * HH + k0 + q8);
      acc[0][tn] = __builtin_amdgcn_mfma_f32_16x16x32_bf16(a[0], bf, acc[0][tn], 0, 0, 0);
      acc[1][tn] = __builtin_amdgcn_mfma_f32_16x16x32_bf16(a[1], bf, acc[1][tn], 0, 0, 0);
    }
  }

  float bias[8];
#pragma unroll
  for (int tn = 0; tn < 8; tn++) bias[tn] = b[tn * 16 + m16];

#pragma unroll
  for (int ti = 0; ti < 2; ti++) {
    const int rbase = bm + ti * 16 + (l >> 4) * 4;
#pragma unroll
    for (int r = 0; r < 4; r++) {
      const int row = rbase + r;
      if (row < NN) {
        const float dv = LAST ? 1.0f : dinv[row];
#pragma unroll
        for (int tn = 0; tn < 8; tn++) {
          const int col = tn * 16 + m16;
          float v = acc[ti][tn][r] + bias[tn];
          if (!LAST) v = dv * fmaxf(v, 0.f);
          Out[(size_t)row * HH + col] = f2bf(v);
        }
      }
    }
  }
}

// ---------------- fused pool + final linear (boundaries precomputed) --------
__global__ __launch_bounds__(128) void pool_final_k(const int* __restrict__ gs,
                                                    const unsigned short* __restrict__ h3,
                                                    const float* __restrict__ Wl,
                                                    const float* __restrict__ bl,
                                                    float* __restrict__ out) {
  const int g = blockIdx.x;
  const int t = threadIdx.x;
  const int beg = gs[g];
  const int end = gs[g + 1];
  float s = 0.f;
  for (int n = beg; n < end; n++) s += bf2f(h3[(size_t)n * HH + t]);
  __shared__ float p[128];
  p[t] = s / (float)max(end - beg, 1);
  __syncthreads();
  float acc = bl[t];
#pragma unroll 8
  for (int h = 0; h < HH; h++) acc += p[h] * Wl[h * TT + t];
  out[(size_t)g * TT + t] = acc;
}

extern "C" void kernel_launch(void* const* d_in, const int* in_sizes, int n_in,
                              void* d_out, int out_size, void* d_ws, size_t ws_size,
                              hipStream_t stream) {
  const int*   x     = (const int*)d_in[0];
  const int*   ei    = (const int*)d_in[1];
  const int*   batch = (const int*)d_in[2];
  const float* emb   = (const float*)d_in[3];
  const float* W1    = (const float*)d_in[4];
  const float* b1    = (const float*)d_in[5];
  const float* W2    = (const float*)d_in[6];
  const float* b2    = (const float*)d_in[7];
  const float* W3    = (const float*)d_in[8];
  const float* b3    = (const float*)d_in[9];
  const float* Wl    = (const float*)d_in[10];
  const float* bl    = (const float*)d_in[11];
  float* out = (float*)d_out;

  // workspace layout (~57 MB)
  unsigned short* bufA = (unsigned short*)d_ws;        // N*H bf16 (h0 / Hs / H3)
  unsigned short* bufB = bufA + (size_t)NN * HH;       // N*H bf16 (Aggs)
  unsigned short* Wt   = bufB + (size_t)NN * HH;       // 3*H*H bf16
  float* dinv   = (float*)(Wt + 3 * HH * HH);          // N
  int*   ptr    = (int*)(dinv + NN);                   // N+1
  int*   cnt    = ptr + NN + 1;                        // N
  int*   bsum   = cnt + NN;                            // 512
  int*   gs     = bsum + 512;                          // G+1
  int*   csr    = gs + GG + 1;                         // E

  hipMemsetAsync(cnt, 0, NN * sizeof(int), stream);

  const int NB = (NN + 255) / 256;

  pre_k<<<DB + NN / 16 + 192, 256, 0, stream>>>(ei, cnt, x, emb, bufA,
                                                W1, W2, W3, Wt);
  scan1_k<<<NB, 256, 0, stream>>>(cnt, ptr, bsum, dinv);
  scan2_k<<<1, 512, 0, stream>>>(bsum, NB);
  scan3_gb_k<<<NB, 256, 0, stream>>>(ptr, bsum, batch, gs);
  fill_k<<<DB, 256, 0, stream>>>(ei, ptr, cnt, csr);

  const int gemm_grid = (NN + 127) / 128;
  const int agg_grid  = NN / 16;   // NN % 16 == 0

  agg_bf_k<true><<<agg_grid, 256, 0, stream>>>(ptr, csr, bufA, dinv, bufB);
  gemm_mfma_k<false><<<gemm_grid, 256, 0, stream>>>(bufB, Wt, b1, dinv, bufA);

  agg_bf_k<false><<<agg_grid, 256, 0, stream>>>(ptr, csr, bufA, dinv, bufB);
  gemm_mfma_k<false><<<gemm_grid, 256, 0, stream>>>(bufB, Wt + HH * HH, b2, dinv, bufA);

  agg_bf_k<false><<<agg_grid, 256, 0, stream>>>(ptr, csr, bufA, dinv, bufB);
  gemm_mfma_k<true><<<gemm_grid, 256, 0, stream>>>(bufB, Wt + 2 * HH * HH, b3, dinv, bufA);

  pool_final_k<<<GG, 128, 0, stream>>>(gs, bufA, Wl, bl, out);
}

// Round 11
// 347.064 us; speedup vs baseline: 1.0163x; 1.0163x over previous
//
#include <hip/hip_runtime.h>

#define NN 100000
#define EE 600000
#define HH 128
#define GG 4000
#define TT 128

typedef short short8 __attribute__((ext_vector_type(8)));
typedef unsigned short ushort8v __attribute__((ext_vector_type(8)));
typedef float floatx4 __attribute__((ext_vector_type(4)));

static __device__ __forceinline__ float bf2f(unsigned short u) {
  union { unsigned int i; float f; } v; v.i = ((unsigned int)u) << 16; return v.f;
}
static __device__ __forceinline__ unsigned short f2bf(float f) {
  union { float f; unsigned int i; } v; v.f = f;
  unsigned int r = (v.i + 0x7FFFu + ((v.i >> 16) & 1u)) >> 16;   // RNE
  return (unsigned short)r;
}

#define DB ((EE / 4 + 255) / 256)    // 586 blocks, 4 edges/thread
#define NB ((NN + 255) / 256)        // 391

// ---------------- degree count: 4 edges/thread (4 atomic chains in flight) --
__global__ __launch_bounds__(256) void deg4_k(const int* __restrict__ ei,
                                              int* __restrict__ cnt) {
  int e4 = (blockIdx.x * 256 + threadIdx.x) * 4;
  if (e4 < EE) {   // EE % 4 == 0
    int4 d = *(const int4*)(ei + EE + e4);
    atomicAdd(&cnt[d.x], 1);
    atomicAdd(&cnt[d.y], 1);
    atomicAdd(&cnt[d.z], 1);
    atomicAdd(&cnt[d.w], 1);
  }
}

// ---------------- scan1: block-local exclusive scan (+dinv fused) -----------
__global__ __launch_bounds__(256) void scan1_k(const int* __restrict__ cnt,
                                               int* __restrict__ ptr,
                                               int* __restrict__ bsum,
                                               float* __restrict__ dinv) {
  const int i = blockIdx.x * 256 + threadIdx.x;
  int v = (i < NN) ? cnt[i] : 0;
  if (i < NN) dinv[i] = rsqrtf((float)v + 1.0f);   // +1 self-loop
  const int lane = threadIdx.x & 63, wid = threadIdx.x >> 6;
  int s = v;
#pragma unroll
  for (int off = 1; off < 64; off <<= 1) {
    int t = __shfl_up(s, off, 64);
    if (lane >= off) s += t;
  }
  __shared__ int wt[4];
  if (lane == 63) wt[wid] = s;
  __syncthreads();
  int wadd = 0;
  for (int w = 0; w < wid; w++) wadd += wt[w];
  int incl = s + wadd;
  if (i < NN) ptr[i] = incl - v;
  if (threadIdx.x == 255) bsum[blockIdx.x] = incl;
}

// ---------------- scan2+3 merged + graph boundaries -------------------------
// Each block reduces bsum[0..bid) itself (1.5 KB, L2-hot), adds to ptr,
// and emits gs[] boundaries (batch sorted).
__global__ __launch_bounds__(256) void scan23_gb_k(int* __restrict__ ptr,
                                                   const int* __restrict__ bsum,
                                                   const int* __restrict__ batch,
                                                   int* __restrict__ gs) {
  const int bid = blockIdx.x;
  const int tid = threadIdx.x;
  // base = sum_{j < bid} bsum[j]
  int s = 0;
  for (int j = tid; j < bid; j += 256) s += bsum[j];
  const int lane = tid & 63, wid = tid >> 6;
#pragma unroll
  for (int off = 32; off > 0; off >>= 1) s += __shfl_down(s, off, 64);
  __shared__ int wt[4];
  if (lane == 0) wt[wid] = s;
  __syncthreads();
  __shared__ int basesh;
  if (tid == 0) basesh = wt[0] + wt[1] + wt[2] + wt[3];
  __syncthreads();
  const int base = basesh;

  const int i = bid * 256 + tid;
  if (i < NN) {
    ptr[i] += base;
    int b0 = batch[i];
    int b1 = (i + 1 < NN) ? batch[i + 1] : GG;
    for (int g = b0 + 1; g <= b1; g++) gs[g] = i + 1;
    if (i == 0) {
      ptr[NN] = EE;
      for (int g = 0; g <= b0; g++) gs[g] = 0;
    }
  }
}

// ---------------- merged: CSR fill (4-edge) + atom encoder + wt -------------
// blocks [0, DB)            : fill csr, 4 edges/thread
// blocks [DB, DB+NN/16)     : atom encoder -> Hs0 = bf16(dinv * h0)
// blocks [DB+NN/16, +192)   : Wt[n][k] = bf16(W[k][n]) for W1,W2,W3
__global__ __launch_bounds__(256) void fill_enc_wt_k(const int* __restrict__ ei,
                                                     const int* __restrict__ ptr,
                                                     int* __restrict__ cnt,
                                                     int* __restrict__ csr,
                                                     const int* __restrict__ x,
                                                     const float* __restrict__ emb,
                                                     const float* __restrict__ dinv,
                                                     unsigned short* __restrict__ h0,
                                                     const float* __restrict__ W1,
                                                     const float* __restrict__ W2,
                                                     const float* __restrict__ W3,
                                                     unsigned short* __restrict__ Wt) {
  if (blockIdx.x < DB) {
    int e4 = (blockIdx.x * 256 + threadIdx.x) * 4;
    if (e4 >= EE) return;
    int4 s = *(const int4*)(ei + e4);
    int4 d = *(const int4*)(ei + EE + e4);
    int o0 = atomicSub(&cnt[d.x], 1) - 1;
    int o1 = atomicSub(&cnt[d.y], 1) - 1;
    int o2 = atomicSub(&cnt[d.z], 1) - 1;
    int o3 = atomicSub(&cnt[d.w], 1) - 1;
    csr[ptr[d.x] + o0] = s.x;
    csr[ptr[d.y] + o1] = s.y;
    csr[ptr[d.z] + o2] = s.z;
    csr[ptr[d.w] + o3] = s.w;
  } else if (blockIdx.x < DB + NN / 16) {
    const int lane = threadIdx.x & 63;
    const int wid  = threadIdx.x >> 6;
    const int l16  = lane & 15;
    const int n = (blockIdx.x - DB) * 16 + wid * 4 + (lane >> 4);
    const int off[9] = {0, 119, 124, 136, 148, 158, 164, 170, 172};
    int xv = (l16 < 9) ? x[n * 9 + l16] : 0;
    float s[8] = {0.f, 0.f, 0.f, 0.f, 0.f, 0.f, 0.f, 0.f};
#pragma unroll
    for (int f = 0; f < 9; f++) {
      int idx = __shfl(xv, (lane & 48) | f, 64) + off[f];
      const float* ep = emb + (size_t)idx * HH + l16 * 8;
      float4 e0 = *(const float4*)ep;
      float4 e1 = *(const float4*)(ep + 4);
      s[0] += e0.x; s[1] += e0.y; s[2] += e0.z; s[3] += e0.w;
      s[4] += e1.x; s[5] += e1.y; s[6] += e1.z; s[7] += e1.w;
    }
    const float dv = dinv[n];
    ushort8v o;
#pragma unroll
    for (int j = 0; j < 8; j++) o[j] = f2bf(dv * s[j]);
    *(ushort8v*)(h0 + (size_t)n * HH + l16 * 8) = o;
  } else {
    int f = (blockIdx.x - DB - NN / 16) * 256 + threadIdx.x;   // 0..49151
    int wsel = f >> 14;
    int r = (f >> 7) & 127;
    int k = f & 127;
    const float* W = (wsel == 0) ? W1 : (wsel == 1) ? W2 : W3;
    Wt[wsel * HH * HH + r * HH + k] = f2bf(W[k * HH + r]);
  }
}

// ---------------- CSR aggregation (masked full-unroll, csr prefetch) --------
// Aggs[n] = bf16( dinv[n] * (Hs[n] + sum_{s in in(n)} Hs[s]) )   (Hs pre-scaled)
__global__ __launch_bounds__(256) void agg_bf_k(const int* __restrict__ ptr,
                                                const int* __restrict__ csr,
                                                const unsigned short* __restrict__ Hs,
                                                const float* __restrict__ dinv,
                                                unsigned short* __restrict__ Aggs) {
  const int lane = threadIdx.x & 63;
  const int wid  = threadIdx.x >> 6;
  const int l16  = lane & 15;
  const int n = blockIdx.x * 16 + wid * 4 + (lane >> 4);   // grid*16 == NN
  const int beg = ptr[n], end = ptr[n + 1];
  const int last = end - 1;
  float acc[8];
  {  // self row
    ushort8v v = *(const ushort8v*)(Hs + (size_t)n * HH + l16 * 8);
#pragma unroll
    for (int j = 0; j < 8; j++) acc[j] = bf2f(v[j]);
  }
  int i = beg;
  if (i < end) {
    int c0 = csr[i];
    int c1 = csr[min(i + 1, last)];
    int c2 = csr[min(i + 2, last)];
    int c3 = csr[min(i + 3, last)];
    while (true) {
      const float m1 = (i + 1 < end) ? 1.f : 0.f;
      const float m2 = (i + 2 < end) ? 1.f : 0.f;
      const float m3 = (i + 3 < end) ? 1.f : 0.f;
      ushort8v v0 = *(const ushort8v*)(Hs + (size_t)c0 * HH + l16 * 8);
      ushort8v v1 = *(const ushort8v*)(Hs + (size_t)c1 * HH + l16 * 8);
      ushort8v v2 = *(const ushort8v*)(Hs + (size_t)c2 * HH + l16 * 8);
      ushort8v v3 = *(const ushort8v*)(Hs + (size_t)c3 * HH + l16 * 8);
      const int ni = i + 4;
      int p0 = c0, p1 = c1, p2 = c2, p3 = c3;
      if (ni < end) {             // prefetch next csr quad (overlaps gathers)
        p0 = csr[ni];
        p1 = csr[min(ni + 1, last)];
        p2 = csr[min(ni + 2, last)];
        p3 = csr[min(ni + 3, last)];
      }
#pragma unroll
      for (int j = 0; j < 8; j++)
        acc[j] += bf2f(v0[j]) + m1 * bf2f(v1[j]) + m2 * bf2f(v2[j]) + m3 * bf2f(v3[j]);
      i = ni;
      if (i >= end) break;
      c0 = p0; c1 = p1; c2 = p2; c3 = p3;
    }
  }
  const float dv = dinv[n];
  ushort8v o;
#pragma unroll
  for (int j = 0; j < 8; j++) o[j] = f2bf(dv * acc[j]);
  *(ushort8v*)(Aggs + (size_t)n * HH + l16 * 8) = o;
}

// ---------------- MFMA GEMM (after aggregation) ----------------
template <bool LAST>
__global__ __launch_bounds__(256) void gemm_mfma_k(const unsigned short* __restrict__ A,
                                                   const unsigned short* __restrict__ Wt,
                                                   const float* __restrict__ b,
                                                   const float* __restrict__ dinv,
                                                   unsigned short* __restrict__ Out) {
  const int w = threadIdx.x >> 6;
  const int l = threadIdx.x & 63;
  const int m16 = l & 15;
  const int q8  = (l >> 4) * 8;
  const int bm  = blockIdx.x * 128 + w * 32;

  floatx4 acc[2][8];
#pragma unroll
  for (int i = 0; i < 2; i++)
#pragma unroll
    for (int j = 0; j < 8; j++) acc[i][j] = (floatx4){0.f, 0.f, 0.f, 0.f};

  for (int q = 0; q < 4; q++) {
    const int k0 = q * 32;
    short8 a[2];
#pragma unroll
    for (int ti = 0; ti < 2; ti++) {
      int row = bm + ti * 16 + m16;
      a[ti] = (row < NN) ? *(const short8*)(A + (size_t)row * HH + k0 + q8)
                         : (short8){0, 0, 0, 0, 0, 0, 0, 0};
    }
#pragma unroll
    for (int tn = 0; tn < 8; tn++) {
      short8 bf = *(const short8*)(Wt + (size_t)(tn * 16 + m16) * HH + k0 + q8);
      acc[0][tn] = __builtin_amdgcn_mfma_f32_16x16x32_bf16(a[0], bf, acc[0][tn], 0, 0, 0);
      acc[1][tn] = __builtin_amdgcn_mfma_f32_16x16x32_bf16(a[1], bf, acc[1][tn], 0, 0, 0);
    }
  }

  float bias[8];
#pragma unroll
  for (int tn = 0; tn < 8; tn++) bias[tn] = b[tn * 16 + m16];

#pragma unroll
  for (int ti = 0; ti < 2; ti++) {
    const int rbase = bm + ti * 16 + (l >> 4) * 4;
#pragma unroll
    for (int r = 0; r < 4; r++) {
      const int row = rbase + r;
      if (row < NN) {
        const float dv = LAST ? 1.0f : dinv[row];
#pragma unroll
        for (int tn = 0; tn < 8; tn++) {
          const int col = tn * 16 + m16;
          float v = acc[ti][tn][r] + bias[tn];
          if (!LAST) v = dv * fmaxf(v, 0.f);
          Out[(size_t)row * HH + col] = f2bf(v);
        }
      }
    }
  }
}

// ---------------- fused pool + final linear (boundaries precomputed) --------
__global__ __launch_bounds__(128) void pool_final_k(const int* __restrict__ gs,
                                                    const unsigned short* __restrict__ h3,
                                                    const float* __restrict__ Wl,
                                                    const float* __restrict__ bl,
                                                    float* __restrict__ out) {
  const int g = blockIdx.x;
  const int t = threadIdx.x;
  const int beg = gs[g];
  const int end = gs[g + 1];
  float s = 0.f;
  for (int n = beg; n < end; n++) s += bf2f(h3[(size_t)n * HH + t]);
  __shared__ float p[128];
  p[t] = s / (float)max(end - beg, 1);
  __syncthreads();
  float acc = bl[t];
#pragma unroll 8
  for (int h = 0; h < HH; h++) acc += p[h] * Wl[h * TT + t];
  out[(size_t)g * TT + t] = acc;
}

extern "C" void kernel_launch(void* const* d_in, const int* in_sizes, int n_in,
                              void* d_out, int out_size, void* d_ws, size_t ws_size,
                              hipStream_t stream) {
  const int*   x     = (const int*)d_in[0];
  const int*   ei    = (const int*)d_in[1];
  const int*   batch = (const int*)d_in[2];
  const float* emb   = (const float*)d_in[3];
  const float* W1    = (const float*)d_in[4];
  const float* b1    = (const float*)d_in[5];
  const float* W2    = (const float*)d_in[6];
  const float* b2    = (const float*)d_in[7];
  const float* W3    = (const float*)d_in[8];
  const float* b3    = (const float*)d_in[9];
  const float* Wl    = (const float*)d_in[10];
  const float* bl    = (const float*)d_in[11];
  float* out = (float*)d_out;

  // workspace layout (~57 MB)
  unsigned short* bufA = (unsigned short*)d_ws;        // N*H bf16 (Hs / H3)
  unsigned short* bufB = bufA + (size_t)NN * HH;       // N*H bf16 (Aggs)
  unsigned short* Wt   = bufB + (size_t)NN * HH;       // 3*H*H bf16
  float* dinv   = (float*)(Wt + 3 * HH * HH);          // N
  int*   ptr    = (int*)(dinv + NN);                   // N+1
  int*   cnt    = ptr + NN + 1;                        // N
  int*   bsum   = cnt + NN;                            // 512
  int*   gs     = bsum + 512;                          // G+1
  int*   csr    = gs + GG + 1;                         // E

  hipMemsetAsync(cnt, 0, NN * sizeof(int), stream);

  deg4_k<<<DB, 256, 0, stream>>>(ei, cnt);
  scan1_k<<<NB, 256, 0, stream>>>(cnt, ptr, bsum, dinv);
  scan23_gb_k<<<NB, 256, 0, stream>>>(ptr, bsum, batch, gs);
  fill_enc_wt_k<<<DB + NN / 16 + 192, 256, 0, stream>>>(ei, ptr, cnt, csr,
                                                        x, emb, dinv, bufA,
                                                        W1, W2, W3, Wt);

  const int gemm_grid = (NN + 127) / 128;
  const int agg_grid  = NN / 16;   // NN % 16 == 0

  agg_bf_k<<<agg_grid, 256, 0, stream>>>(ptr, csr, bufA, dinv, bufB);
  gemm_mfma_k<false><<<gemm_grid, 256, 0, stream>>>(bufB, Wt, b1, dinv, bufA);

  agg_bf_k<<<agg_grid, 256, 0, stream>>>(ptr, csr, bufA, dinv, bufB);
  gemm_mfma_k<false><<<gemm_grid, 256, 0, stream>>>(bufB, Wt + HH * HH, b2, dinv, bufA);

  agg_bf_k<<<agg_grid, 256, 0, stream>>>(ptr, csr, bufA, dinv, bufB);
  gemm_mfma_k<true><<<gemm_grid, 256, 0, stream>>>(bufB, Wt + 2 * HH * HH, b3, dinv, bufA);

  pool_final_k<<<GG, 128, 0, stream>>>(gs, bufA, Wl, bl, out);
}